// Round 7
// baseline (806.345 us; speedup 1.0000x reference)
//
#include <hip/hip_runtime.h>
#include <math.h>

#define BATCH 8
#define NPTS 4096
#define SSAMP 256
#define KNBR 128
#define GGRID 2025

typedef __attribute__((ext_vector_type(8))) short bf16x8;
typedef __attribute__((ext_vector_type(8))) unsigned short u16x8;
typedef __attribute__((ext_vector_type(4))) float f32x4;
#define MFMA16(a, b, c) __builtin_amdgcn_mfma_f32_16x16x32_bf16((a), (b), (c), 0, 0, 0)

__device__ __forceinline__ float lrelu01(float v) { return v > 0.f ? v : 0.01f * v; }
__device__ __forceinline__ unsigned short f2bf(float f) {
    unsigned u = __float_as_uint(f);
    unsigned r = (u + 0x7FFFu + ((u >> 16) & 1u)) >> 16;
    return (unsigned short)r;
}
__device__ __forceinline__ unsigned long long umax64(unsigned long long a, unsigned long long b) {
    return a > b ? a : b;
}

// ---------------------------------------------------------------- fused front: fps (blocks 0-7) +
// xform (blocks 8..4103) + preconv (blocks 4104..7907), all 512-thread blocks.
// fps: 8 pts/lane, u64 key tree depth-3, butterfly = 3 super-stages of 4-way max,
// parity-buffered single barrier/step, LDS float4 pcache for winner coords.
__global__ void __launch_bounds__(512) front_kernel(
    const float* __restrict__ pos, float* __restrict__ newpos,
    const float* __restrict__ Wt, const float* __restrict__ bt, unsigned short* __restrict__ x,
    const float* __restrict__ Wc1, const float* __restrict__ Wc2, const float* __restrict__ Wc3,
    const float* __restrict__ We1, const float* __restrict__ We2,
    const float* __restrict__ Wf12, const float* __restrict__ Wf22,
    unsigned short* __restrict__ W1T, unsigned short* __restrict__ W2T,
    unsigned short* __restrict__ W3T, unsigned short* __restrict__ We1T,
    unsigned short* __restrict__ We2T, unsigned short* __restrict__ Wf12T,
    unsigned short* __restrict__ Wf22T) {
    __shared__ float4 pcache[NPTS];                  // 64 KB (fps blocks only)
    __shared__ unsigned long long rk[2][8];
    int blk = blockIdx.x, t = threadIdx.x;
    if (blk < 8) {
        int b = blk;
        int wave = t >> 6, lane = t & 63;
        const float* P = pos + (size_t)b * NPTS * 3;
        float px[8], py[8], pz[8], mind[8];
#pragma unroll
        for (int j = 0; j < 8; ++j) {
            int n = t + 512 * j;
            float X = P[n * 3 + 0], Y = P[n * 3 + 1], Z = P[n * 3 + 2];
            px[j] = X; py[j] = Y; pz[j] = Z;
            pcache[n] = make_float4(X, Y, Z, 0.f);
            mind[j] = 3.402823466e+38f;
        }
        float cx = P[0], cy = P[1], cz = P[2];
        if (t == 0) {
            newpos[(size_t)b * SSAMP * 3 + 0] = cx;
            newpos[(size_t)b * SSAMP * 3 + 1] = cy;
            newpos[(size_t)b * SSAMP * 3 + 2] = cz;
        }
        __syncthreads();                             // pcache ready
        for (int s = 1; s < SSAMP; ++s) {
            int p = s & 1;
            unsigned long long k[8];
#pragma unroll
            for (int j = 0; j < 8; ++j) {
                float dx = __fsub_rn(px[j], cx), dy = __fsub_rn(py[j], cy), dz = __fsub_rn(pz[j], cz);
                float d = __fadd_rn(__fadd_rn(__fmul_rn(dx, dx), __fmul_rn(dy, dy)), __fmul_rn(dz, dz));
                mind[j] = fminf(mind[j], d);
                k[j] = ((unsigned long long)__float_as_uint(mind[j]) << 32)
                     | (unsigned)~(unsigned)(t + 512 * j);
            }
#pragma unroll
            for (int st = 4; st > 0; st >>= 1)
#pragma unroll
                for (int j = 0; j < st; ++j) k[j] = umax64(k[j], k[j + st]);
            unsigned long long key = k[0];
            // butterfly: 3 super-stages of 4-way max (shuffles per stage independent)
            {
                unsigned long long a = __shfl_xor(key, 1, 64);
                unsigned long long b2 = __shfl_xor(key, 2, 64);
                unsigned long long c = __shfl_xor(key, 3, 64);
                key = umax64(umax64(key, a), umax64(b2, c));
                a = __shfl_xor(key, 4, 64);
                b2 = __shfl_xor(key, 8, 64);
                c = __shfl_xor(key, 12, 64);
                key = umax64(umax64(key, a), umax64(b2, c));
                a = __shfl_xor(key, 16, 64);
                b2 = __shfl_xor(key, 32, 64);
                c = __shfl_xor(key, 48, 64);
                key = umax64(umax64(key, a), umax64(b2, c));
            }
            if (lane == 0) rk[p][wave] = key;
            __syncthreads();
            const ulonglong2* rp = (const ulonglong2*)rk[p];
            ulonglong2 A = rp[0], B = rp[1], C = rp[2], D = rp[3];
            unsigned long long bk = umax64(umax64(umax64(A.x, A.y), umax64(B.x, B.y)),
                                           umax64(umax64(C.x, C.y), umax64(D.x, D.y)));
            int nx = (int)(~(unsigned)(bk & 0xFFFFFFFFull));
            float4 c4 = pcache[nx];
            cx = c4.x; cy = c4.y; cz = c4.z;
            if (t == 0) {
                newpos[((size_t)b * SSAMP + s) * 3 + 0] = cx;
                newpos[((size_t)b * SSAMP + s) * 3 + 1] = cy;
                newpos[((size_t)b * SSAMP + s) * 3 + 2] = cz;
            }
        }
        return;
    }
    if (blk < 8 + 4096) {
        // xform: x = bf16(lrelu(pos @ Wt + bt)), 2,097,152 elems
        int o = (blk - 8) * 512 + t;
        int c = o & 63, pi = o >> 6;
        const float* pr = pos + (size_t)pi * 3;
        float v = fmaf(pr[2], Wt[128 + c], fmaf(pr[1], Wt[64 + c], fmaf(pr[0], Wt[c], bt[c])));
        x[o] = f2bf(lrelu01(v));
        return;
    }
    // preconv: bf16 [n][k] transposes, 1,947,648 elems
    int o = (blk - 4104) * 512 + t;
    const int S1 = 6144, S2 = 8192, S3 = 65536, S4 = 294912, S5 = 1048576, S6 = 262144;
    if (o < S1) { int n = o / 96, k = o - n * 96; W1T[o] = f2bf(k < 67 ? Wc1[k * 64 + n] : 0.f); return; }
    o -= S1;
    if (o < S2) { int n = o >> 6, k = o & 63; W2T[o] = f2bf(Wc2[k * 128 + n]); return; }
    o -= S2;
    if (o < S3) { int n = o >> 7, k = o & 127; W3T[o] = f2bf(Wc3[k * 512 + n]); return; }
    o -= S3;
    if (o < S4) { int n = o / 576, k = o - n * 576; We1T[o] = f2bf(k < 515 ? We1[k * 512 + n] : 0.f); return; }
    o -= S4;
    if (o < S5) { int n = o >> 9, k = o & 511; We2T[o] = f2bf(We2[k * 2048 + n]); return; }
    o -= S5;
    if (o < S6) { int n = o >> 9, k = o & 511; Wf12T[o] = f2bf(Wf12[k * 512 + n]); return; }
    o -= S6;
    { int n = o >> 9, k = o & 511; Wf22T[o] = f2bf(Wf22[k * 512 + n]); }
}

// ---------------------------------------------------------------- 3) radius ball query (one wave per (b,s))
__global__ void __launch_bounds__(256) ballq_kernel(const float* __restrict__ pos,
                                                    const float* __restrict__ newpos,
                                                    int* __restrict__ nidx) {
    int w = blockIdx.x * 4 + (threadIdx.x >> 6);
    int lane = threadIdx.x & 63;
    int b = w >> 8;
    const float* P = pos + (size_t)b * NPTS * 3;
    float qx = newpos[w * 3 + 0], qy = newpos[w * 3 + 1], qz = newpos[w * 3 + 2];
    int* out = nidx + (size_t)w * KNBR;
    int base = 0;
    for (int c = 0; c < 64; ++c) {
        int n = c * 64 + lane;
        float dx = __fsub_rn(P[n * 3 + 0], qx);
        float dy = __fsub_rn(P[n * 3 + 1], qy);
        float dz = __fsub_rn(P[n * 3 + 2], qz);
        float d2 = __fadd_rn(__fadd_rn(__fmul_rn(dx, dx), __fmul_rn(dy, dy)), __fmul_rn(dz, dz));
        bool in = (d2 <= 0.04f);
        unsigned long long mask = __ballot(in);
        if (in) {
            int p = base + __popcll(mask & ((1ull << lane) - 1ull));
            if (p < KNBR) out[p] = n;
        }
        base += __popcll(mask);
        if (base >= KNBR) break;
    }
    for (int p = base + lane; p < KNBR; p += 64) out[p] = -1;
}

// ---------------------------------------------------------------- 4) fused PointConv via bf16 MFMA + encin epilogue
__global__ void __launch_bounds__(256, 3) pointconv_kernel(
    const unsigned short* __restrict__ xbf, const float* __restrict__ pos,
    const float* __restrict__ newpos, const int* __restrict__ nidx,
    const unsigned short* __restrict__ W1T, const unsigned short* __restrict__ W2T,
    const unsigned short* __restrict__ W3T,
    const float* __restrict__ bc1, const float* __restrict__ bc2, const float* __restrict__ bc3,
    unsigned short* __restrict__ encin) {
    __shared__ __align__(16) unsigned char smem[53760];
    unsigned short* featl = (unsigned short*)smem;           // [128][104] bf16 (phase A)
    unsigned short* h2    = (unsigned short*)smem;           // [128][136] bf16 (aliases feat)
    unsigned short* h1    = (unsigned short*)(smem + 34816); // [128][72] bf16
    float* mred = (float*)(smem + 34816);                    // [4][512] fp32 (aliases h1, used in L3)
    int*   vld  = (int*)(smem + 53248);                      // [128]

    int bs = blockIdx.x, b = bs >> 8, t = threadIdx.x;
    int wave = t >> 6, lane = t & 63, quad = lane >> 4, l16 = lane & 15;
    const float* npp = newpos + (size_t)bs * 3;
    float q0 = npp[0], q1 = npp[1], q2 = npp[2];
    if (t < 128) vld[t] = nidx[(size_t)bs * KNBR + t];
    __syncthreads();

    int vbits = 0;
#pragma unroll
    for (int i = 0; i < 2; ++i)
#pragma unroll
        for (int reg = 0; reg < 4; ++reg)
            if (vld[(2 * wave + i) * 16 + quad * 4 + reg] >= 0) vbits |= 1 << (i * 4 + reg);

    // ---- Phase A: vectorized staging, thread pair per row
    {
        int sr = t >> 1, sh = t & 1;
        int n = vld[sr];
        int ns = n < 0 ? 0 : n;
        const u16x8* src = (const u16x8*)(xbf + ((size_t)b * NPTS + ns) * 64);
        u16x8 z8 = {0, 0, 0, 0, 0, 0, 0, 0};
        if (sh == 0) {
#pragma unroll
            for (int j = 0; j < 6; ++j)
                *(u16x8*)&featl[sr * 104 + j * 8] = (n >= 0) ? src[j] : z8;
        } else {
#pragma unroll
            for (int j = 0; j < 2; ++j)
                *(u16x8*)&featl[sr * 104 + 48 + j * 8] = (n >= 0) ? src[6 + j] : z8;
            const float* pp = pos + ((size_t)b * NPTS + ns) * 3;
            u16x8 dv = z8;
            if (n >= 0) {
                dv[0] = (short)f2bf(__fsub_rn(pp[0], q0));
                dv[1] = (short)f2bf(__fsub_rn(pp[1], q1));
                dv[2] = (short)f2bf(__fsub_rn(pp[2], q2));
            }
            *(u16x8*)&featl[sr * 104 + 64] = dv;
            *(u16x8*)&featl[sr * 104 + 72] = z8;
            *(u16x8*)&featl[sr * 104 + 80] = z8;
            *(u16x8*)&featl[sr * 104 + 88] = z8;
        }
    }
    __syncthreads();

    // ---- Layer 1 MFMA: M=128, N=64, K=96
    {
        f32x4 acc[2][4];
#pragma unroll
        for (int i = 0; i < 2; ++i)
#pragma unroll
            for (int nt = 0; nt < 4; ++nt) acc[i][nt] = (f32x4){0.f, 0.f, 0.f, 0.f};
#pragma unroll
        for (int ks = 0; ks < 3; ++ks) {
            bf16x8 afr[2];
#pragma unroll
            for (int i = 0; i < 2; ++i)
                afr[i] = *(const bf16x8*)&featl[((2 * wave + i) * 16 + l16) * 104 + ks * 32 + quad * 8];
#pragma unroll
            for (int nt = 0; nt < 4; ++nt) {
                bf16x8 bfr = *(const bf16x8*)(W1T + (nt * 16 + l16) * 96 + ks * 32 + quad * 8);
                acc[0][nt] = MFMA16(afr[0], bfr, acc[0][nt]);
                acc[1][nt] = MFMA16(afr[1], bfr, acc[1][nt]);
            }
        }
#pragma unroll
        for (int i = 0; i < 2; ++i)
#pragma unroll
            for (int nt = 0; nt < 4; ++nt) {
                int col = nt * 16 + l16;
                float bias = bc1[col];
#pragma unroll
                for (int reg = 0; reg < 4; ++reg) {
                    int row = (2 * wave + i) * 16 + quad * 4 + reg;
                    h1[row * 72 + col] = f2bf(lrelu01(acc[i][nt][reg] + bias));
                }
            }
    }
    __syncthreads();

    // ---- Layer 2 MFMA: M=128, N=128, K=64 (h2 aliases feat)
    {
        f32x4 acc[2][8];
#pragma unroll
        for (int i = 0; i < 2; ++i)
#pragma unroll
            for (int nt = 0; nt < 8; ++nt) acc[i][nt] = (f32x4){0.f, 0.f, 0.f, 0.f};
#pragma unroll
        for (int ks = 0; ks < 2; ++ks) {
            bf16x8 afr[2];
#pragma unroll
            for (int i = 0; i < 2; ++i)
                afr[i] = *(const bf16x8*)&h1[((2 * wave + i) * 16 + l16) * 72 + ks * 32 + quad * 8];
#pragma unroll
            for (int nt = 0; nt < 8; ++nt) {
                bf16x8 bfr = *(const bf16x8*)(W2T + (nt * 16 + l16) * 64 + ks * 32 + quad * 8);
                acc[0][nt] = MFMA16(afr[0], bfr, acc[0][nt]);
                acc[1][nt] = MFMA16(afr[1], bfr, acc[1][nt]);
            }
        }
        __syncthreads();   // all reads of feat/h1 done before h2 overwrite
#pragma unroll
        for (int i = 0; i < 2; ++i)
#pragma unroll
            for (int nt = 0; nt < 8; ++nt) {
                int col = nt * 16 + l16;
                float bias = bc2[col];
#pragma unroll
                for (int reg = 0; reg < 4; ++reg) {
                    int row = (2 * wave + i) * 16 + quad * 4 + reg;
                    h2[row * 136 + col] = f2bf(lrelu01(acc[i][nt][reg] + bias));
                }
            }
    }
    __syncthreads();

    // ---- Layer 3 MFMA: M=128, N=512, K=128; masked max (mred aliases h1 - safe, h1 dead)
    for (int c3 = 0; c3 < 4; ++c3) {
        f32x4 acc[2][8];
#pragma unroll
        for (int i = 0; i < 2; ++i)
#pragma unroll
            for (int nt = 0; nt < 8; ++nt) acc[i][nt] = (f32x4){0.f, 0.f, 0.f, 0.f};
#pragma unroll
        for (int ks = 0; ks < 4; ++ks) {
            bf16x8 afr[2];
#pragma unroll
            for (int i = 0; i < 2; ++i)
                afr[i] = *(const bf16x8*)&h2[((2 * wave + i) * 16 + l16) * 136 + ks * 32 + quad * 8];
#pragma unroll
            for (int nt = 0; nt < 8; ++nt) {
                bf16x8 bfr = *(const bf16x8*)(W3T + ((size_t)((c3 * 8 + nt) * 16 + l16)) * 128 + ks * 32 + quad * 8);
                acc[0][nt] = MFMA16(afr[0], bfr, acc[0][nt]);
                acc[1][nt] = MFMA16(afr[1], bfr, acc[1][nt]);
            }
        }
#pragma unroll
        for (int nt = 0; nt < 8; ++nt) {
            float vmax = -3.402823466e+38f;
#pragma unroll
            for (int i = 0; i < 2; ++i)
#pragma unroll
                for (int reg = 0; reg < 4; ++reg)
                    if (vbits & (1 << (i * 4 + reg))) vmax = fmaxf(vmax, acc[i][nt][reg]);
            vmax = fmaxf(vmax, __shfl_xor(vmax, 16));
            vmax = fmaxf(vmax, __shfl_xor(vmax, 32));
            if (lane < 16) mred[wave * 512 + (c3 * 8 + nt) * 16 + l16] = vmax;
        }
    }
    __syncthreads();
    // ---- epilogue: write encin row (bf16, K padded to 576): [agg | newpos | 0]
    unsigned short* erow = encin + (size_t)bs * 576;
    for (int c = t; c < 576; c += 256) {
        unsigned short v;
        if (c < 512) {
            float m4 = fmaxf(fmaxf(mred[c], mred[512 + c]), fmaxf(mred[1024 + c], mred[1536 + c]));
            v = f2bf(lrelu01(m4 + bc3[c]));
        } else if (c < 515) {
            v = f2bf(c == 512 ? q0 : (c == 513 ? q1 : q2));
        } else v = 0;
        erow[c] = v;
    }
}

// ---------------------------------------------------------------- generic bf16 MFMA GEMM: 128x128 tile
__global__ void __launch_bounds__(256, 3) mfma_gemm(
    const unsigned short* __restrict__ A, const unsigned short* __restrict__ BT,
    const float* __restrict__ bias, float* __restrict__ outf, unsigned short* __restrict__ outh,
    int M, int Ka, int Ncols, int act) {
    __shared__ __align__(16) unsigned short As[128 * 72];
    int t = threadIdx.x;
    int wave = t >> 6, lane = t & 63, quad = lane >> 4, l16 = lane & 15;
    int row0 = blockIdx.x * 128, col0 = blockIdx.y * 128;
    f32x4 acc[2][8];
#pragma unroll
    for (int i = 0; i < 2; ++i)
#pragma unroll
        for (int nt = 0; nt < 8; ++nt) acc[i][nt] = (f32x4){0.f, 0.f, 0.f, 0.f};
    int nk = Ka >> 6;
    int sr = t >> 1, sh = t & 1;
    int grow = row0 + sr; if (grow > M - 1) grow = M - 1;
    const unsigned short* Arow = A + (size_t)grow * Ka + sh * 32;
    for (int ks = 0; ks < nk; ++ks) {
        u16x8 av[4];
#pragma unroll
        for (int j = 0; j < 4; ++j) av[j] = *(const u16x8*)(Arow + ks * 64 + j * 8);
        __syncthreads();
#pragma unroll
        for (int j = 0; j < 4; ++j) *(u16x8*)&As[sr * 72 + sh * 32 + j * 8] = av[j];
        __syncthreads();
#pragma unroll
        for (int ks2 = 0; ks2 < 2; ++ks2) {
            bf16x8 afr[2];
            afr[0] = *(const bf16x8*)&As[((2 * wave) * 16 + l16) * 72 + ks2 * 32 + quad * 8];
            afr[1] = *(const bf16x8*)&As[((2 * wave + 1) * 16 + l16) * 72 + ks2 * 32 + quad * 8];
#pragma unroll
            for (int nt = 0; nt < 8; ++nt) {
                bf16x8 bfr = *(const bf16x8*)(BT + (size_t)(col0 + nt * 16 + l16) * Ka + ks * 64 + ks2 * 32 + quad * 8);
                acc[0][nt] = MFMA16(afr[0], bfr, acc[0][nt]);
                acc[1][nt] = MFMA16(afr[1], bfr, acc[1][nt]);
            }
        }
    }
#pragma unroll
    for (int i = 0; i < 2; ++i)
#pragma unroll
        for (int nt = 0; nt < 8; ++nt) {
            int col = col0 + nt * 16 + l16;
            float bv = bias[col];
#pragma unroll
            for (int reg = 0; reg < 4; ++reg) {
                int row = row0 + (2 * wave + i) * 16 + quad * 4 + reg;
                if (row < M) {
                    float v = acc[i][nt][reg] + bv;
                    if (act == 1) v = fmaxf(v, 0.f);
                    else if (act == 2) v = lrelu01(v);
                    if (outh) outh[(size_t)row * Ncols + col] = f2bf(v);
                    else outf[(size_t)row * Ncols + col] = v;
                }
            }
        }
}

// ---------------------------------------------------------------- 8) vote aggregation (256 blocks)
__global__ void __launch_bounds__(256) votes_kernel(const float* __restrict__ e, float* __restrict__ z) {
    __shared__ float red[8][32][2];
    int blk = blockIdx.x;
    int b = blk >> 5, c0 = (blk & 31) << 5;
    int t = threadIdx.x, c = t & 31, sg = t >> 5;
    const float* eb = e + (size_t)b * SSAMP * 2048;
    float num = 0.f, den = 0.f;
    for (int si = 0; si < 32; ++si) {
        int s = sg * 32 + si;
        float mean = eb[(size_t)s * 2048 + c0 + c];
        float lv = eb[(size_t)s * 2048 + 1024 + c0 + c];
        float sd = expf(0.5f * lv);
        num += mean / sd;
        den += 1.f / sd;
    }
    red[sg][c][0] = num; red[sg][c][1] = den;
    __syncthreads();
    if (sg == 0) {
        float n = 0.f, d = 0.f;
#pragma unroll
        for (int k = 0; k < 8; ++k) { n += red[k][c][0]; d += red[k][c][1]; }
        z[b * 1024 + c0 + c] = n / d;
    }
}

// ---------------------------------------------------------------- 9) u = z @ Wf[0:1024] + b (K-split x4)
__global__ void __launch_bounds__(256) ukern(const float* __restrict__ z,
                                             const float* __restrict__ Wf11, const float* __restrict__ bf11,
                                             const float* __restrict__ Wf21, const float* __restrict__ bf21,
                                             float* __restrict__ u1, float* __restrict__ u2) {
    __shared__ float zt[1024 * 8];      // zt[ci*8+r]
    __shared__ float red[4][64][8];
    const float* W = blockIdx.y ? Wf21 : Wf11;
    const float* bias = blockIdx.y ? bf21 : bf11;
    float* u = blockIdx.y ? u2 : u1;
    int t = threadIdx.x;
#pragma unroll
    for (int i = 0; i < 32; ++i) {
        int o = t + i * 256;
        zt[(o & 1023) * 8 + (o >> 10)] = z[o];
    }
    __syncthreads();
    int c64 = t & 63, kc = t >> 6;
    int co = blockIdx.x * 64 + c64;
    float acc[8];
#pragma unroll
    for (int r = 0; r < 8; ++r) acc[r] = 0.f;
    for (int i = 0; i < 256; ++i) {
        int ci = kc * 256 + i;
        float w = W[(size_t)ci * 512 + co];
        const float4* zp = (const float4*)&zt[ci * 8];
        float4 z0 = zp[0], z1 = zp[1];
        acc[0] = fmaf(z0.x, w, acc[0]); acc[1] = fmaf(z0.y, w, acc[1]);
        acc[2] = fmaf(z0.z, w, acc[2]); acc[3] = fmaf(z0.w, w, acc[3]);
        acc[4] = fmaf(z1.x, w, acc[4]); acc[5] = fmaf(z1.y, w, acc[5]);
        acc[6] = fmaf(z1.z, w, acc[6]); acc[7] = fmaf(z1.w, w, acc[7]);
    }
#pragma unroll
    for (int r = 0; r < 8; ++r) red[kc][c64][r] = acc[r];
    __syncthreads();
    if (kc == 0) {
#pragma unroll
        for (int r = 0; r < 8; ++r) {
            float v = red[0][c64][r] + red[1][c64][r] + red[2][c64][r] + red[3][c64][r] + bias[co];
            u[r * 512 + co] = v;
        }
    }
}

// ---------------------------------------------------------------- 10) fold1 first layer -> bf16
__global__ void fold1_kernel(const float* __restrict__ u1, const float* __restrict__ Wf11,
                             unsigned short* __restrict__ f1) {
    int o = blockIdx.x * 256 + threadIdx.x;          // 8*2025*512 exact
    int co = o & 511;
    int rg = o >> 9;
    int b = rg / 2025;
    int g = rg - b * 2025;
    int i = g / 45, j = g - i * 45;
    float gx = (j == 44) ? 0.3f : (float)(-0.3 + j * (0.6 / 44.0));
    float gy = (i == 44) ? 0.3f : (float)(-0.3 + i * (0.6 / 44.0));
    float v = u1[(b << 9) + co];
    v = fmaf(gx, Wf11[1024 * 512 + co], v);
    v = fmaf(gy, Wf11[1025 * 512 + co], v);
    f1[o] = f2bf(fmaxf(v, 0.f));
}

// ---------------------------------------------------------------- 13) fold2 first layer -> bf16
__global__ void fold2_kernel(const float* __restrict__ u2, const float* __restrict__ Wf21,
                             const float* __restrict__ pts, unsigned short* __restrict__ f2) {
    int o = blockIdx.x * 256 + threadIdx.x;
    int co = o & 511;
    int rg = o >> 9;
    int b = rg / 2025;
    float p0 = pts[rg * 3 + 0], p1 = pts[rg * 3 + 1], p2 = pts[rg * 3 + 2];
    float v = u2[(b << 9) + co];
    v = fmaf(p0, Wf21[1024 * 512 + co], v);
    v = fmaf(p1, Wf21[1025 * 512 + co], v);
    v = fmaf(p2, Wf21[1026 * 512 + co], v);
    f2[o] = f2bf(fmaxf(v, 0.f));
}

// ---------------------------------------------------------------- final 512->3 (one row per thread)
__global__ void smallout_kernel(const unsigned short* __restrict__ H, const float* __restrict__ Wf,
                                const float* __restrict__ bf, float* __restrict__ out, int rows) {
    int rg = blockIdx.x * 256 + threadIdx.x;
    if (rg >= rows) return;
    const unsigned int* h = (const unsigned int*)(H + (size_t)rg * 512);
    float a0 = bf[0], a1 = bf[1], a2 = bf[2];
#pragma unroll 4
    for (int q = 0; q < 256; ++q) {
        unsigned int p = h[q];
        float e0 = __uint_as_float(p << 16);
        float e1 = __uint_as_float(p & 0xFFFF0000u);
        int k = q * 2;
        a0 = fmaf(e0, Wf[k * 3 + 0], a0);
        a1 = fmaf(e0, Wf[k * 3 + 1], a1);
        a2 = fmaf(e0, Wf[k * 3 + 2], a2);
        a0 = fmaf(e1, Wf[k * 3 + 3], a0);
        a1 = fmaf(e1, Wf[k * 3 + 4], a1);
        a2 = fmaf(e1, Wf[k * 3 + 5], a2);
    }
    out[rg * 3 + 0] = a0;
    out[rg * 3 + 1] = a1;
    out[rg * 3 + 2] = a2;
}

extern "C" void kernel_launch(void* const* d_in, const int* in_sizes, int n_in,
                              void* d_out, int out_size, void* d_ws, size_t ws_size,
                              hipStream_t stream) {
    const float* pos  = (const float*)d_in[0];
    const float* Wt   = (const float*)d_in[1];
    const float* bt   = (const float*)d_in[2];
    const float* Wc1  = (const float*)d_in[3];
    const float* bc1  = (const float*)d_in[4];
    const float* Wc2  = (const float*)d_in[5];
    const float* bc2  = (const float*)d_in[6];
    const float* Wc3  = (const float*)d_in[7];
    const float* bc3  = (const float*)d_in[8];
    const float* We1  = (const float*)d_in[9];
    const float* be1  = (const float*)d_in[10];
    const float* We2  = (const float*)d_in[11];
    const float* be2  = (const float*)d_in[12];
    const float* Wf11 = (const float*)d_in[13];
    const float* bf11 = (const float*)d_in[14];
    const float* Wf12 = (const float*)d_in[15];
    const float* bf12 = (const float*)d_in[16];
    const float* Wf13 = (const float*)d_in[17];
    const float* bf13 = (const float*)d_in[18];
    const float* Wf21 = (const float*)d_in[19];
    const float* bf21 = (const float*)d_in[20];
    const float* Wf22 = (const float*)d_in[21];
    const float* bf22 = (const float*)d_in[22];
    const float* Wf23 = (const float*)d_in[23];
    const float* bf23 = (const float*)d_in[24];
    float* out = (float*)d_out;

    float* wsf = (float*)d_ws;
    size_t off = 0;
    unsigned short* xbf   = (unsigned short*)(wsf + off); off += 1048576;  // [B*N][64] bf16
    unsigned short* encinh= (unsigned short*)(wsf + off); off += 589824;   // [2048][576] bf16
    unsigned short* e1h   = (unsigned short*)(wsf + off); off += 524288;   // [2048][512] bf16
    float* e    = wsf + off; off += 4194304;   // [2048][2048] fp32
    unsigned short* f1h   = (unsigned short*)(wsf + off); off += 4147200;  // [16200][512] bf16
    unsigned short* h12h  = (unsigned short*)(wsf + off); off += 4147200;  // [16200][512] bf16
    float* zb   = wsf + off; off += 8192;      // [8][1024]
    float* u1   = wsf + off; off += 4096;
    float* u2   = wsf + off; off += 4096;
    float* pts  = wsf + off; off += 48600;     // [16200][3]
    float* newp = wsf + off; off += 6144;      // [B,S,3]
    int*   nix   = (int*)(wsf + off); off += 262144;
    unsigned short* W1T   = (unsigned short*)(wsf + off); off += 3072;     // 64x96
    unsigned short* W2T   = (unsigned short*)(wsf + off); off += 4096;     // 128x64
    unsigned short* W3T   = (unsigned short*)(wsf + off); off += 32768;    // 512x128
    unsigned short* We1T  = (unsigned short*)(wsf + off); off += 147456;   // 512x576
    unsigned short* We2T  = (unsigned short*)(wsf + off); off += 524288;   // 2048x512
    unsigned short* Wf12T = (unsigned short*)(wsf + off); off += 131072;   // 512x512
    unsigned short* Wf22T = (unsigned short*)(wsf + off); off += 131072;   // 512x512

    // fused front: fps (8 blocks) + xform (4096) + preconv (3804), 512-thread blocks
    front_kernel<<<7908, 512, 0, stream>>>(pos, newp, Wt, bt, xbf,
                                           Wc1, Wc2, Wc3, We1, We2, Wf12, Wf22,
                                           W1T, W2T, W3T, We1T, We2T, Wf12T, Wf22T);
    ballq_kernel<<<512, 256, 0, stream>>>(pos, newp, nix);
    pointconv_kernel<<<2048, 256, 0, stream>>>(xbf, pos, newp, nix, W1T, W2T, W3T,
                                               bc1, bc2, bc3, encinh);
    mfma_gemm<<<dim3(16, 4), 256, 0, stream>>>(encinh, We1T, be1, nullptr, e1h, 2048, 576, 512, 2);
    mfma_gemm<<<dim3(16, 16), 256, 0, stream>>>(e1h, We2T, be2, e, nullptr, 2048, 512, 2048, 0);
    votes_kernel<<<256, 256, 0, stream>>>(e, zb);
    ukern<<<dim3(8, 2), 256, 0, stream>>>(zb, Wf11, bf11, Wf21, bf21, u1, u2);
    fold1_kernel<<<32400, 256, 0, stream>>>(u1, Wf11, f1h);
    mfma_gemm<<<dim3(127, 4), 256, 0, stream>>>(f1h, Wf12T, bf12, nullptr, h12h, 16200, 512, 512, 1);
    smallout_kernel<<<64, 256, 0, stream>>>(h12h, Wf13, bf13, pts, 16200);
    fold2_kernel<<<32400, 256, 0, stream>>>(u2, Wf21, pts, f1h);
    mfma_gemm<<<dim3(127, 4), 256, 0, stream>>>(f1h, Wf22T, bf22, nullptr, h12h, 16200, 512, 512, 1);
    smallout_kernel<<<64, 256, 0, stream>>>(h12h, Wf23, bf23, out, 16200);
}

// Round 8
// 792.559 us; speedup vs baseline: 1.0174x; 1.0174x over previous
//
#include <hip/hip_runtime.h>
#include <math.h>

#define BATCH 8
#define NPTS 4096
#define SSAMP 256
#define KNBR 128
#define GGRID 2025

typedef __attribute__((ext_vector_type(8))) short bf16x8;
typedef __attribute__((ext_vector_type(8))) unsigned short u16x8;
typedef __attribute__((ext_vector_type(4))) float f32x4;
#define MFMA16(a, b, c) __builtin_amdgcn_mfma_f32_16x16x32_bf16((a), (b), (c), 0, 0, 0)

__device__ __forceinline__ float lrelu01(float v) { return v > 0.f ? v : 0.01f * v; }
__device__ __forceinline__ unsigned short f2bf(float f) {
    unsigned u = __float_as_uint(f);
    unsigned r = (u + 0x7FFFu + ((u >> 16) & 1u)) >> 16;
    return (unsigned short)r;
}
__device__ __forceinline__ unsigned long long umax64(unsigned long long a, unsigned long long b) {
    return a > b ? a : b;
}

// ---------------------------------------------------------------- fused front (256-thr blocks):
// fps (blocks 0-7) + xform (8..8199) + preconv (8200..15807).
// fps: 16 pts/lane, depth-4 register key tree, 3-super-stage 4-way-max butterfly,
// parity-buffered rk + single barrier/step, LDS pcache for winner coords, and
// *** newpos buffered in LDS *** (per-step global store would force a vmcnt(0)
// drain before s_barrier on the critical path) -- written once after the loop.
__global__ void __launch_bounds__(256) front_kernel(
    const float* __restrict__ pos, float* __restrict__ newpos,
    const float* __restrict__ Wt, const float* __restrict__ bt, unsigned short* __restrict__ x,
    const float* __restrict__ Wc1, const float* __restrict__ Wc2, const float* __restrict__ Wc3,
    const float* __restrict__ We1, const float* __restrict__ We2,
    const float* __restrict__ Wf12, const float* __restrict__ Wf22,
    unsigned short* __restrict__ W1T, unsigned short* __restrict__ W2T,
    unsigned short* __restrict__ W3T, unsigned short* __restrict__ We1T,
    unsigned short* __restrict__ We2T, unsigned short* __restrict__ Wf12T,
    unsigned short* __restrict__ Wf22T) {
    __shared__ float4 pcache[NPTS];                  // 64 KB (fps blocks only)
    __shared__ unsigned long long rk[2][4];
    __shared__ float npbuf[SSAMP * 3];               // 3 KB: per-step winner coords
    int blk = blockIdx.x, t = threadIdx.x;
    if (blk < 8) {
        int b = blk;
        int wave = t >> 6, lane = t & 63;
        const float* P = pos + (size_t)b * NPTS * 3;
        float px[16], py[16], pz[16], mind[16];
#pragma unroll
        for (int j = 0; j < 16; ++j) {
            int n = t + 256 * j;
            float X = P[n * 3 + 0], Y = P[n * 3 + 1], Z = P[n * 3 + 2];
            px[j] = X; py[j] = Y; pz[j] = Z;
            pcache[n] = make_float4(X, Y, Z, 0.f);
            mind[j] = 3.402823466e+38f;
        }
        float cx = P[0], cy = P[1], cz = P[2];
        if (t == 0) { npbuf[0] = cx; npbuf[1] = cy; npbuf[2] = cz; }
        __syncthreads();                             // pcache ready
        for (int s = 1; s < SSAMP; ++s) {
            int p = s & 1;
            unsigned long long k[16];
#pragma unroll
            for (int j = 0; j < 16; ++j) {
                float dx = __fsub_rn(px[j], cx), dy = __fsub_rn(py[j], cy), dz = __fsub_rn(pz[j], cz);
                float d = __fadd_rn(__fadd_rn(__fmul_rn(dx, dx), __fmul_rn(dy, dy)), __fmul_rn(dz, dz));
                mind[j] = fminf(mind[j], d);
                k[j] = ((unsigned long long)__float_as_uint(mind[j]) << 32)
                     | (unsigned)~(unsigned)(t + 256 * j);
            }
#pragma unroll
            for (int st = 8; st > 0; st >>= 1)
#pragma unroll
                for (int j = 0; j < st; ++j) k[j] = umax64(k[j], k[j + st]);
            unsigned long long key = k[0];
            // butterfly: 3 super-stages of 4-way max (independent shuffles per stage)
            {
                unsigned long long a = __shfl_xor(key, 1, 64);
                unsigned long long b2 = __shfl_xor(key, 2, 64);
                unsigned long long c = __shfl_xor(key, 3, 64);
                key = umax64(umax64(key, a), umax64(b2, c));
                a = __shfl_xor(key, 4, 64);
                b2 = __shfl_xor(key, 8, 64);
                c = __shfl_xor(key, 12, 64);
                key = umax64(umax64(key, a), umax64(b2, c));
                a = __shfl_xor(key, 16, 64);
                b2 = __shfl_xor(key, 32, 64);
                c = __shfl_xor(key, 48, 64);
                key = umax64(umax64(key, a), umax64(b2, c));
            }
            if (lane == 0) rk[p][wave] = key;
            __syncthreads();
            const ulonglong2* rp = (const ulonglong2*)rk[p];
            ulonglong2 A = rp[0], B = rp[1];
            unsigned long long bk = umax64(umax64(A.x, A.y), umax64(B.x, B.y));
            int nx = (int)(~(unsigned)(bk & 0xFFFFFFFFull));
            float4 c4 = pcache[nx];
            cx = c4.x; cy = c4.y; cz = c4.z;
            if (t == 0) {
                npbuf[s * 3 + 0] = cx;
                npbuf[s * 3 + 1] = cy;
                npbuf[s * 3 + 2] = cz;
            }
        }
        __syncthreads();                             // last npbuf write visible
        float* np = newpos + (size_t)b * SSAMP * 3;
#pragma unroll
        for (int i = 0; i < 3; ++i) np[t + 256 * i] = npbuf[t + 256 * i];
        return;
    }
    if (blk < 8 + 8192) {
        // xform: x = bf16(lrelu(pos @ Wt + bt)), 2,097,152 elems
        int o = (blk - 8) * 256 + t;
        int c = o & 63, pi = o >> 6;
        const float* pr = pos + (size_t)pi * 3;
        float v = fmaf(pr[2], Wt[128 + c], fmaf(pr[1], Wt[64 + c], fmaf(pr[0], Wt[c], bt[c])));
        x[o] = f2bf(lrelu01(v));
        return;
    }
    // preconv: bf16 [n][k] transposes, 1,947,648 = 7608*256 elems
    int o = (blk - 8200) * 256 + t;
    const int S1 = 6144, S2 = 8192, S3 = 65536, S4 = 294912, S5 = 1048576, S6 = 262144;
    if (o < S1) { int n = o / 96, k = o - n * 96; W1T[o] = f2bf(k < 67 ? Wc1[k * 64 + n] : 0.f); return; }
    o -= S1;
    if (o < S2) { int n = o >> 6, k = o & 63; W2T[o] = f2bf(Wc2[k * 128 + n]); return; }
    o -= S2;
    if (o < S3) { int n = o >> 7, k = o & 127; W3T[o] = f2bf(Wc3[k * 512 + n]); return; }
    o -= S3;
    if (o < S4) { int n = o / 576, k = o - n * 576; We1T[o] = f2bf(k < 515 ? We1[k * 512 + n] : 0.f); return; }
    o -= S4;
    if (o < S5) { int n = o >> 9, k = o & 511; We2T[o] = f2bf(We2[k * 2048 + n]); return; }
    o -= S5;
    if (o < S6) { int n = o >> 9, k = o & 511; Wf12T[o] = f2bf(Wf12[k * 512 + n]); return; }
    o -= S6;
    { int n = o >> 9, k = o & 511; Wf22T[o] = f2bf(Wf22[k * 512 + n]); }
}

// ---------------------------------------------------------------- 3) radius ball query (one wave per (b,s))
__global__ void __launch_bounds__(256) ballq_kernel(const float* __restrict__ pos,
                                                    const float* __restrict__ newpos,
                                                    int* __restrict__ nidx) {
    int w = blockIdx.x * 4 + (threadIdx.x >> 6);
    int lane = threadIdx.x & 63;
    int b = w >> 8;
    const float* P = pos + (size_t)b * NPTS * 3;
    float qx = newpos[w * 3 + 0], qy = newpos[w * 3 + 1], qz = newpos[w * 3 + 2];
    int* out = nidx + (size_t)w * KNBR;
    int base = 0;
    for (int c = 0; c < 64; ++c) {
        int n = c * 64 + lane;
        float dx = __fsub_rn(P[n * 3 + 0], qx);
        float dy = __fsub_rn(P[n * 3 + 1], qy);
        float dz = __fsub_rn(P[n * 3 + 2], qz);
        float d2 = __fadd_rn(__fadd_rn(__fmul_rn(dx, dx), __fmul_rn(dy, dy)), __fmul_rn(dz, dz));
        bool in = (d2 <= 0.04f);
        unsigned long long mask = __ballot(in);
        if (in) {
            int p = base + __popcll(mask & ((1ull << lane) - 1ull));
            if (p < KNBR) out[p] = n;
        }
        base += __popcll(mask);
        if (base >= KNBR) break;
    }
    for (int p = base + lane; p < KNBR; p += 64) out[p] = -1;
}

// ---------------------------------------------------------------- 4) fused PointConv via bf16 MFMA + encin epilogue
__global__ void __launch_bounds__(256, 3) pointconv_kernel(
    const unsigned short* __restrict__ xbf, const float* __restrict__ pos,
    const float* __restrict__ newpos, const int* __restrict__ nidx,
    const unsigned short* __restrict__ W1T, const unsigned short* __restrict__ W2T,
    const unsigned short* __restrict__ W3T,
    const float* __restrict__ bc1, const float* __restrict__ bc2, const float* __restrict__ bc3,
    unsigned short* __restrict__ encin) {
    __shared__ __align__(16) unsigned char smem[53760];
    unsigned short* featl = (unsigned short*)smem;           // [128][104] bf16 (phase A)
    unsigned short* h2    = (unsigned short*)smem;           // [128][136] bf16 (aliases feat)
    unsigned short* h1    = (unsigned short*)(smem + 34816); // [128][72] bf16
    float* mred = (float*)(smem + 34816);                    // [4][512] fp32 (aliases h1, used in L3)
    int*   vld  = (int*)(smem + 53248);                      // [128]

    int bs = blockIdx.x, b = bs >> 8, t = threadIdx.x;
    int wave = t >> 6, lane = t & 63, quad = lane >> 4, l16 = lane & 15;
    const float* npp = newpos + (size_t)bs * 3;
    float q0 = npp[0], q1 = npp[1], q2 = npp[2];
    if (t < 128) vld[t] = nidx[(size_t)bs * KNBR + t];
    __syncthreads();

    int vbits = 0;
#pragma unroll
    for (int i = 0; i < 2; ++i)
#pragma unroll
        for (int reg = 0; reg < 4; ++reg)
            if (vld[(2 * wave + i) * 16 + quad * 4 + reg] >= 0) vbits |= 1 << (i * 4 + reg);

    // ---- Phase A: vectorized staging, thread pair per row
    {
        int sr = t >> 1, sh = t & 1;
        int n = vld[sr];
        int ns = n < 0 ? 0 : n;
        const u16x8* src = (const u16x8*)(xbf + ((size_t)b * NPTS + ns) * 64);
        u16x8 z8 = {0, 0, 0, 0, 0, 0, 0, 0};
        if (sh == 0) {
#pragma unroll
            for (int j = 0; j < 6; ++j)
                *(u16x8*)&featl[sr * 104 + j * 8] = (n >= 0) ? src[j] : z8;
        } else {
#pragma unroll
            for (int j = 0; j < 2; ++j)
                *(u16x8*)&featl[sr * 104 + 48 + j * 8] = (n >= 0) ? src[6 + j] : z8;
            const float* pp = pos + ((size_t)b * NPTS + ns) * 3;
            u16x8 dv = z8;
            if (n >= 0) {
                dv[0] = (short)f2bf(__fsub_rn(pp[0], q0));
                dv[1] = (short)f2bf(__fsub_rn(pp[1], q1));
                dv[2] = (short)f2bf(__fsub_rn(pp[2], q2));
            }
            *(u16x8*)&featl[sr * 104 + 64] = dv;
            *(u16x8*)&featl[sr * 104 + 72] = z8;
            *(u16x8*)&featl[sr * 104 + 80] = z8;
            *(u16x8*)&featl[sr * 104 + 88] = z8;
        }
    }
    __syncthreads();

    // ---- Layer 1 MFMA: M=128, N=64, K=96
    {
        f32x4 acc[2][4];
#pragma unroll
        for (int i = 0; i < 2; ++i)
#pragma unroll
            for (int nt = 0; nt < 4; ++nt) acc[i][nt] = (f32x4){0.f, 0.f, 0.f, 0.f};
#pragma unroll
        for (int ks = 0; ks < 3; ++ks) {
            bf16x8 afr[2];
#pragma unroll
            for (int i = 0; i < 2; ++i)
                afr[i] = *(const bf16x8*)&featl[((2 * wave + i) * 16 + l16) * 104 + ks * 32 + quad * 8];
#pragma unroll
            for (int nt = 0; nt < 4; ++nt) {
                bf16x8 bfr = *(const bf16x8*)(W1T + (nt * 16 + l16) * 96 + ks * 32 + quad * 8);
                acc[0][nt] = MFMA16(afr[0], bfr, acc[0][nt]);
                acc[1][nt] = MFMA16(afr[1], bfr, acc[1][nt]);
            }
        }
#pragma unroll
        for (int i = 0; i < 2; ++i)
#pragma unroll
            for (int nt = 0; nt < 4; ++nt) {
                int col = nt * 16 + l16;
                float bias = bc1[col];
#pragma unroll
                for (int reg = 0; reg < 4; ++reg) {
                    int row = (2 * wave + i) * 16 + quad * 4 + reg;
                    h1[row * 72 + col] = f2bf(lrelu01(acc[i][nt][reg] + bias));
                }
            }
    }
    __syncthreads();

    // ---- Layer 2 MFMA: M=128, N=128, K=64 (h2 aliases feat)
    {
        f32x4 acc[2][8];
#pragma unroll
        for (int i = 0; i < 2; ++i)
#pragma unroll
            for (int nt = 0; nt < 8; ++nt) acc[i][nt] = (f32x4){0.f, 0.f, 0.f, 0.f};
#pragma unroll
        for (int ks = 0; ks < 2; ++ks) {
            bf16x8 afr[2];
#pragma unroll
            for (int i = 0; i < 2; ++i)
                afr[i] = *(const bf16x8*)&h1[((2 * wave + i) * 16 + l16) * 72 + ks * 32 + quad * 8];
#pragma unroll
            for (int nt = 0; nt < 8; ++nt) {
                bf16x8 bfr = *(const bf16x8*)(W2T + (nt * 16 + l16) * 64 + ks * 32 + quad * 8);
                acc[0][nt] = MFMA16(afr[0], bfr, acc[0][nt]);
                acc[1][nt] = MFMA16(afr[1], bfr, acc[1][nt]);
            }
        }
        __syncthreads();   // all reads of feat/h1 done before h2 overwrite
#pragma unroll
        for (int i = 0; i < 2; ++i)
#pragma unroll
            for (int nt = 0; nt < 8; ++nt) {
                int col = nt * 16 + l16;
                float bias = bc2[col];
#pragma unroll
                for (int reg = 0; reg < 4; ++reg) {
                    int row = (2 * wave + i) * 16 + quad * 4 + reg;
                    h2[row * 136 + col] = f2bf(lrelu01(acc[i][nt][reg] + bias));
                }
            }
    }
    __syncthreads();

    // ---- Layer 3 MFMA: M=128, N=512, K=128; masked max (mred aliases h1 - safe, h1 dead)
    for (int c3 = 0; c3 < 4; ++c3) {
        f32x4 acc[2][8];
#pragma unroll
        for (int i = 0; i < 2; ++i)
#pragma unroll
            for (int nt = 0; nt < 8; ++nt) acc[i][nt] = (f32x4){0.f, 0.f, 0.f, 0.f};
#pragma unroll
        for (int ks = 0; ks < 4; ++ks) {
            bf16x8 afr[2];
#pragma unroll
            for (int i = 0; i < 2; ++i)
                afr[i] = *(const bf16x8*)&h2[((2 * wave + i) * 16 + l16) * 136 + ks * 32 + quad * 8];
#pragma unroll
            for (int nt = 0; nt < 8; ++nt) {
                bf16x8 bfr = *(const bf16x8*)(W3T + ((size_t)((c3 * 8 + nt) * 16 + l16)) * 128 + ks * 32 + quad * 8);
                acc[0][nt] = MFMA16(afr[0], bfr, acc[0][nt]);
                acc[1][nt] = MFMA16(afr[1], bfr, acc[1][nt]);
            }
        }
#pragma unroll
        for (int nt = 0; nt < 8; ++nt) {
            float vmax = -3.402823466e+38f;
#pragma unroll
            for (int i = 0; i < 2; ++i)
#pragma unroll
                for (int reg = 0; reg < 4; ++reg)
                    if (vbits & (1 << (i * 4 + reg))) vmax = fmaxf(vmax, acc[i][nt][reg]);
            vmax = fmaxf(vmax, __shfl_xor(vmax, 16));
            vmax = fmaxf(vmax, __shfl_xor(vmax, 32));
            if (lane < 16) mred[wave * 512 + (c3 * 8 + nt) * 16 + l16] = vmax;
        }
    }
    __syncthreads();
    // ---- epilogue: write encin row (bf16, K padded to 576): [agg | newpos | 0]
    unsigned short* erow = encin + (size_t)bs * 576;
    for (int c = t; c < 576; c += 256) {
        unsigned short v;
        if (c < 512) {
            float m4 = fmaxf(fmaxf(mred[c], mred[512 + c]), fmaxf(mred[1024 + c], mred[1536 + c]));
            v = f2bf(lrelu01(m4 + bc3[c]));
        } else if (c < 515) {
            v = f2bf(c == 512 ? q0 : (c == 513 ? q1 : q2));
        } else v = 0;
        erow[c] = v;
    }
}

// ---------------------------------------------------------------- generic bf16 MFMA GEMM: 128x128 tile
__global__ void __launch_bounds__(256, 3) mfma_gemm(
    const unsigned short* __restrict__ A, const unsigned short* __restrict__ BT,
    const float* __restrict__ bias, float* __restrict__ outf, unsigned short* __restrict__ outh,
    int M, int Ka, int Ncols, int act) {
    __shared__ __align__(16) unsigned short As[128 * 72];
    int t = threadIdx.x;
    int wave = t >> 6, lane = t & 63, quad = lane >> 4, l16 = lane & 15;
    int row0 = blockIdx.x * 128, col0 = blockIdx.y * 128;
    f32x4 acc[2][8];
#pragma unroll
    for (int i = 0; i < 2; ++i)
#pragma unroll
        for (int nt = 0; nt < 8; ++nt) acc[i][nt] = (f32x4){0.f, 0.f, 0.f, 0.f};
    int nk = Ka >> 6;
    int sr = t >> 1, sh = t & 1;
    int grow = row0 + sr; if (grow > M - 1) grow = M - 1;
    const unsigned short* Arow = A + (size_t)grow * Ka + sh * 32;
    for (int ks = 0; ks < nk; ++ks) {
        u16x8 av[4];
#pragma unroll
        for (int j = 0; j < 4; ++j) av[j] = *(const u16x8*)(Arow + ks * 64 + j * 8);
        __syncthreads();
#pragma unroll
        for (int j = 0; j < 4; ++j) *(u16x8*)&As[sr * 72 + sh * 32 + j * 8] = av[j];
        __syncthreads();
#pragma unroll
        for (int ks2 = 0; ks2 < 2; ++ks2) {
            bf16x8 afr[2];
            afr[0] = *(const bf16x8*)&As[((2 * wave) * 16 + l16) * 72 + ks2 * 32 + quad * 8];
            afr[1] = *(const bf16x8*)&As[((2 * wave + 1) * 16 + l16) * 72 + ks2 * 32 + quad * 8];
#pragma unroll
            for (int nt = 0; nt < 8; ++nt) {
                bf16x8 bfr = *(const bf16x8*)(BT + (size_t)(col0 + nt * 16 + l16) * Ka + ks * 64 + ks2 * 32 + quad * 8);
                acc[0][nt] = MFMA16(afr[0], bfr, acc[0][nt]);
                acc[1][nt] = MFMA16(afr[1], bfr, acc[1][nt]);
            }
        }
    }
#pragma unroll
    for (int i = 0; i < 2; ++i)
#pragma unroll
        for (int nt = 0; nt < 8; ++nt) {
            int col = col0 + nt * 16 + l16;
            float bv = bias[col];
#pragma unroll
            for (int reg = 0; reg < 4; ++reg) {
                int row = row0 + (2 * wave + i) * 16 + quad * 4 + reg;
                if (row < M) {
                    float v = acc[i][nt][reg] + bv;
                    if (act == 1) v = fmaxf(v, 0.f);
                    else if (act == 2) v = lrelu01(v);
                    if (outh) outh[(size_t)row * Ncols + col] = f2bf(v);
                    else outf[(size_t)row * Ncols + col] = v;
                }
            }
        }
}

// ---------------------------------------------------------------- 8) vote aggregation (256 blocks)
__global__ void __launch_bounds__(256) votes_kernel(const float* __restrict__ e, float* __restrict__ z) {
    __shared__ float red[8][32][2];
    int blk = blockIdx.x;
    int b = blk >> 5, c0 = (blk & 31) << 5;
    int t = threadIdx.x, c = t & 31, sg = t >> 5;
    const float* eb = e + (size_t)b * SSAMP * 2048;
    float num = 0.f, den = 0.f;
    for (int si = 0; si < 32; ++si) {
        int s = sg * 32 + si;
        float mean = eb[(size_t)s * 2048 + c0 + c];
        float lv = eb[(size_t)s * 2048 + 1024 + c0 + c];
        float sd = expf(0.5f * lv);
        num += mean / sd;
        den += 1.f / sd;
    }
    red[sg][c][0] = num; red[sg][c][1] = den;
    __syncthreads();
    if (sg == 0) {
        float n = 0.f, d = 0.f;
#pragma unroll
        for (int k = 0; k < 8; ++k) { n += red[k][c][0]; d += red[k][c][1]; }
        z[b * 1024 + c0 + c] = n / d;
    }
}

// ---------------------------------------------------------------- 9) u = z @ Wf[0:1024] + b (K-split x4)
__global__ void __launch_bounds__(256) ukern(const float* __restrict__ z,
                                             const float* __restrict__ Wf11, const float* __restrict__ bf11,
                                             const float* __restrict__ Wf21, const float* __restrict__ bf21,
                                             float* __restrict__ u1, float* __restrict__ u2) {
    __shared__ float zt[1024 * 8];      // zt[ci*8+r]
    __shared__ float red[4][64][8];
    const float* W = blockIdx.y ? Wf21 : Wf11;
    const float* bias = blockIdx.y ? bf21 : bf11;
    float* u = blockIdx.y ? u2 : u1;
    int t = threadIdx.x;
#pragma unroll
    for (int i = 0; i < 32; ++i) {
        int o = t + i * 256;
        zt[(o & 1023) * 8 + (o >> 10)] = z[o];
    }
    __syncthreads();
    int c64 = t & 63, kc = t >> 6;
    int co = blockIdx.x * 64 + c64;
    float acc[8];
#pragma unroll
    for (int r = 0; r < 8; ++r) acc[r] = 0.f;
    for (int i = 0; i < 256; ++i) {
        int ci = kc * 256 + i;
        float w = W[(size_t)ci * 512 + co];
        const float4* zp = (const float4*)&zt[ci * 8];
        float4 z0 = zp[0], z1 = zp[1];
        acc[0] = fmaf(z0.x, w, acc[0]); acc[1] = fmaf(z0.y, w, acc[1]);
        acc[2] = fmaf(z0.z, w, acc[2]); acc[3] = fmaf(z0.w, w, acc[3]);
        acc[4] = fmaf(z1.x, w, acc[4]); acc[5] = fmaf(z1.y, w, acc[5]);
        acc[6] = fmaf(z1.z, w, acc[6]); acc[7] = fmaf(z1.w, w, acc[7]);
    }
#pragma unroll
    for (int r = 0; r < 8; ++r) red[kc][c64][r] = acc[r];
    __syncthreads();
    if (kc == 0) {
#pragma unroll
        for (int r = 0; r < 8; ++r) {
            float v = red[0][c64][r] + red[1][c64][r] + red[2][c64][r] + red[3][c64][r] + bias[co];
            u[r * 512 + co] = v;
        }
    }
}

// ---------------------------------------------------------------- 10) fold1 first layer -> bf16
__global__ void fold1_kernel(const float* __restrict__ u1, const float* __restrict__ Wf11,
                             unsigned short* __restrict__ f1) {
    int o = blockIdx.x * 256 + threadIdx.x;          // 8*2025*512 exact
    int co = o & 511;
    int rg = o >> 9;
    int b = rg / 2025;
    int g = rg - b * 2025;
    int i = g / 45, j = g - i * 45;
    float gx = (j == 44) ? 0.3f : (float)(-0.3 + j * (0.6 / 44.0));
    float gy = (i == 44) ? 0.3f : (float)(-0.3 + i * (0.6 / 44.0));
    float v = u1[(b << 9) + co];
    v = fmaf(gx, Wf11[1024 * 512 + co], v);
    v = fmaf(gy, Wf11[1025 * 512 + co], v);
    f1[o] = f2bf(fmaxf(v, 0.f));
}

// ---------------------------------------------------------------- 13) fold2 first layer -> bf16
__global__ void fold2_kernel(const float* __restrict__ u2, const float* __restrict__ Wf21,
                             const float* __restrict__ pts, unsigned short* __restrict__ f2) {
    int o = blockIdx.x * 256 + threadIdx.x;
    int co = o & 511;
    int rg = o >> 9;
    int b = rg / 2025;
    float p0 = pts[rg * 3 + 0], p1 = pts[rg * 3 + 1], p2 = pts[rg * 3 + 2];
    float v = u2[(b << 9) + co];
    v = fmaf(p0, Wf21[1024 * 512 + co], v);
    v = fmaf(p1, Wf21[1025 * 512 + co], v);
    v = fmaf(p2, Wf21[1026 * 512 + co], v);
    f2[o] = f2bf(fmaxf(v, 0.f));
}

// ---------------------------------------------------------------- final 512->3 (one row per thread)
__global__ void smallout_kernel(const unsigned short* __restrict__ H, const float* __restrict__ Wf,
                                const float* __restrict__ bf, float* __restrict__ out, int rows) {
    int rg = blockIdx.x * 256 + threadIdx.x;
    if (rg >= rows) return;
    const unsigned int* h = (const unsigned int*)(H + (size_t)rg * 512);
    float a0 = bf[0], a1 = bf[1], a2 = bf[2];
#pragma unroll 4
    for (int q = 0; q < 256; ++q) {
        unsigned int p = h[q];
        float e0 = __uint_as_float(p << 16);
        float e1 = __uint_as_float(p & 0xFFFF0000u);
        int k = q * 2;
        a0 = fmaf(e0, Wf[k * 3 + 0], a0);
        a1 = fmaf(e0, Wf[k * 3 + 1], a1);
        a2 = fmaf(e0, Wf[k * 3 + 2], a2);
        a0 = fmaf(e1, Wf[k * 3 + 3], a0);
        a1 = fmaf(e1, Wf[k * 3 + 4], a1);
        a2 = fmaf(e1, Wf[k * 3 + 5], a2);
    }
    out[rg * 3 + 0] = a0;
    out[rg * 3 + 1] = a1;
    out[rg * 3 + 2] = a2;
}

extern "C" void kernel_launch(void* const* d_in, const int* in_sizes, int n_in,
                              void* d_out, int out_size, void* d_ws, size_t ws_size,
                              hipStream_t stream) {
    const float* pos  = (const float*)d_in[0];
    const float* Wt   = (const float*)d_in[1];
    const float* bt   = (const float*)d_in[2];
    const float* Wc1  = (const float*)d_in[3];
    const float* bc1  = (const float*)d_in[4];
    const float* Wc2  = (const float*)d_in[5];
    const float* bc2  = (const float*)d_in[6];
    const float* Wc3  = (const float*)d_in[7];
    const float* bc3  = (const float*)d_in[8];
    const float* We1  = (const float*)d_in[9];
    const float* be1  = (const float*)d_in[10];
    const float* We2  = (const float*)d_in[11];
    const float* be2  = (const float*)d_in[12];
    const float* Wf11 = (const float*)d_in[13];
    const float* bf11 = (const float*)d_in[14];
    const float* Wf12 = (const float*)d_in[15];
    const float* bf12 = (const float*)d_in[16];
    const float* Wf13 = (const float*)d_in[17];
    const float* bf13 = (const float*)d_in[18];
    const float* Wf21 = (const float*)d_in[19];
    const float* bf21 = (const float*)d_in[20];
    const float* Wf22 = (const float*)d_in[21];
    const float* bf22 = (const float*)d_in[22];
    const float* Wf23 = (const float*)d_in[23];
    const float* bf23 = (const float*)d_in[24];
    float* out = (float*)d_out;

    float* wsf = (float*)d_ws;
    size_t off = 0;
    unsigned short* xbf   = (unsigned short*)(wsf + off); off += 1048576;  // [B*N][64] bf16
    unsigned short* encinh= (unsigned short*)(wsf + off); off += 589824;   // [2048][576] bf16
    unsigned short* e1h   = (unsigned short*)(wsf + off); off += 524288;   // [2048][512] bf16
    float* e    = wsf + off; off += 4194304;   // [2048][2048] fp32
    unsigned short* f1h   = (unsigned short*)(wsf + off); off += 4147200;  // [16200][512] bf16
    unsigned short* h12h  = (unsigned short*)(wsf + off); off += 4147200;  // [16200][512] bf16
    float* zb   = wsf + off; off += 8192;      // [8][1024]
    float* u1   = wsf + off; off += 4096;
    float* u2   = wsf + off; off += 4096;
    float* pts  = wsf + off; off += 48600;     // [16200][3]
    float* newp = wsf + off; off += 6144;      // [B,S,3]
    int*   nix   = (int*)(wsf + off); off += 262144;
    unsigned short* W1T   = (unsigned short*)(wsf + off); off += 3072;     // 64x96
    unsigned short* W2T   = (unsigned short*)(wsf + off); off += 4096;     // 128x64
    unsigned short* W3T   = (unsigned short*)(wsf + off); off += 32768;    // 512x128
    unsigned short* We1T  = (unsigned short*)(wsf + off); off += 147456;   // 512x576
    unsigned short* We2T  = (unsigned short*)(wsf + off); off += 524288;   // 2048x512
    unsigned short* Wf12T = (unsigned short*)(wsf + off); off += 131072;   // 512x512
    unsigned short* Wf22T = (unsigned short*)(wsf + off); off += 131072;   // 512x512

    // fused front: fps (8 blocks) + xform (8192) + preconv (7608), 256-thread blocks
    front_kernel<<<15808, 256, 0, stream>>>(pos, newp, Wt, bt, xbf,
                                            Wc1, Wc2, Wc3, We1, We2, Wf12, Wf22,
                                            W1T, W2T, W3T, We1T, We2T, Wf12T, Wf22T);
    ballq_kernel<<<512, 256, 0, stream>>>(pos, newp, nix);
    pointconv_kernel<<<2048, 256, 0, stream>>>(xbf, pos, newp, nix, W1T, W2T, W3T,
                                               bc1, bc2, bc3, encinh);
    mfma_gemm<<<dim3(16, 4), 256, 0, stream>>>(encinh, We1T, be1, nullptr, e1h, 2048, 576, 512, 2);
    mfma_gemm<<<dim3(16, 16), 256, 0, stream>>>(e1h, We2T, be2, e, nullptr, 2048, 512, 2048, 0);
    votes_kernel<<<256, 256, 0, stream>>>(e, zb);
    ukern<<<dim3(8, 2), 256, 0, stream>>>(zb, Wf11, bf11, Wf21, bf21, u1, u2);
    fold1_kernel<<<32400, 256, 0, stream>>>(u1, Wf11, f1h);
    mfma_gemm<<<dim3(127, 4), 256, 0, stream>>>(f1h, Wf12T, bf12, nullptr, h12h, 16200, 512, 512, 1);
    smallout_kernel<<<64, 256, 0, stream>>>(h12h, Wf13, bf13, pts, 16200);
    fold2_kernel<<<32400, 256, 0, stream>>>(u2, Wf21, pts, f1h);
    mfma_gemm<<<dim3(127, 4), 256, 0, stream>>>(f1h, Wf22T, bf22, nullptr, h12h, 16200, 512, 512, 1);
    smallout_kernel<<<64, 256, 0, stream>>>(h12h, Wf23, bf23, out, 16200);
}

// Round 9
// 681.945 us; speedup vs baseline: 1.1824x; 1.1622x over previous
//
#include <hip/hip_runtime.h>
#include <math.h>

#define BATCH 8
#define NPTS 4096
#define SSAMP 256
#define KNBR 128
#define GGRID 2025

typedef __attribute__((ext_vector_type(8))) short bf16x8;
typedef __attribute__((ext_vector_type(8))) unsigned short u16x8;
typedef __attribute__((ext_vector_type(4))) float f32x4;
#define MFMA16(a, b, c) __builtin_amdgcn_mfma_f32_16x16x32_bf16((a), (b), (c), 0, 0, 0)

__device__ __forceinline__ float lrelu01(float v) { return v > 0.f ? v : 0.01f * v; }
__device__ __forceinline__ unsigned short f2bf(float f) {
    unsigned u = __float_as_uint(f);
    unsigned r = (u + 0x7FFFu + ((u >> 16) & 1u)) >> 16;
    return (unsigned short)r;
}
__device__ __forceinline__ unsigned long long umax64(unsigned long long a, unsigned long long b) {
    return a > b ? a : b;
}

// ---------------------------------------------------------------- 0) weight preconvert to bf16 [n][k]
__global__ void preconv_kernel(const float* __restrict__ Wc1, const float* __restrict__ Wc2,
                               const float* __restrict__ Wc3, const float* __restrict__ We1,
                               const float* __restrict__ We2, const float* __restrict__ Wf12,
                               const float* __restrict__ Wf22,
                               unsigned short* __restrict__ W1T, unsigned short* __restrict__ W2T,
                               unsigned short* __restrict__ W3T, unsigned short* __restrict__ We1T,
                               unsigned short* __restrict__ We2T, unsigned short* __restrict__ Wf12T,
                               unsigned short* __restrict__ Wf22T) {
    int o = blockIdx.x * 256 + threadIdx.x;
    const int S1 = 6144, S2 = 8192, S3 = 65536, S4 = 294912, S5 = 1048576, S6 = 262144;
    if (o < S1) { int n = o / 96, k = o - n * 96; W1T[o] = f2bf(k < 67 ? Wc1[k * 64 + n] : 0.f); return; }
    o -= S1;
    if (o < S2) { int n = o >> 6, k = o & 63; W2T[o] = f2bf(Wc2[k * 128 + n]); return; }
    o -= S2;
    if (o < S3) { int n = o >> 7, k = o & 127; W3T[o] = f2bf(Wc3[k * 512 + n]); return; }
    o -= S3;
    if (o < S4) { int n = o / 576, k = o - n * 576; We1T[o] = f2bf(k < 515 ? We1[k * 512 + n] : 0.f); return; }
    o -= S4;
    if (o < S5) { int n = o >> 9, k = o & 511; We2T[o] = f2bf(We2[k * 2048 + n]); return; }
    o -= S5;
    if (o < S6) { int n = o >> 9, k = o & 511; Wf12T[o] = f2bf(Wf12[k * 512 + n]); return; }
    o -= S6;
    { int n = o >> 9, k = o & 511; Wf22T[o] = f2bf(Wf22[k * 512 + n]); }
}

// ---------------------------------------------------------------- stage1: fps producers (blocks 0-7)
// + per-(b,s) consumers (blocks 8..2055): spin on prog[b] -> ballq -> fused-xform feat -> MFMA
// pointconv -> encin row. Producer releases prog[b]=s every 8 steps (threadfence + agent atomic).
__global__ void __launch_bounds__(256, 3) stage1_kernel(
    const float* __restrict__ pos, float* __restrict__ newpos, int* __restrict__ prog,
    const float* __restrict__ Wt, const float* __restrict__ bt,
    const unsigned short* __restrict__ W1T, const unsigned short* __restrict__ W2T,
    const unsigned short* __restrict__ W3T,
    const float* __restrict__ bc1, const float* __restrict__ bc2, const float* __restrict__ bc3,
    unsigned short* __restrict__ encin) {
    __shared__ __align__(16) unsigned char smem[53760];
    int blk = blockIdx.x, t = threadIdx.x;
    int wave = t >> 6, lane = t & 63;

    if (blk < 8) {
        // ================= FPS producer =================
        float* pxs = (float*)smem;                   // [4096]
        float* pys = (float*)(smem + 16384);
        float* pzs = (float*)(smem + 32768);
        float* npb = (float*)(smem + 49152);         // [768]
        unsigned long long* rk = (unsigned long long*)(smem + 52224);  // [2][4]
        int b = blk;
        const float* P = pos + (size_t)b * NPTS * 3;
        float* np = newpos + (size_t)b * SSAMP * 3;
        float px[16], py[16], pz[16], mind[16];
#pragma unroll
        for (int j = 0; j < 16; ++j) {
            int n = t + 256 * j;
            float X = P[n * 3 + 0], Y = P[n * 3 + 1], Z = P[n * 3 + 2];
            px[j] = X; py[j] = Y; pz[j] = Z;
            pxs[n] = X; pys[n] = Y; pzs[n] = Z;
            mind[j] = 3.402823466e+38f;
        }
        float cx = P[0], cy = P[1], cz = P[2];
        if (t == 0) { npb[0] = cx; npb[1] = cy; npb[2] = cz; }
        __syncthreads();
        for (int s = 1; s < SSAMP; ++s) {
            int p = s & 1;
            unsigned long long k[16];
#pragma unroll
            for (int j = 0; j < 16; ++j) {
                float dx = __fsub_rn(px[j], cx), dy = __fsub_rn(py[j], cy), dz = __fsub_rn(pz[j], cz);
                float d = __fadd_rn(__fadd_rn(__fmul_rn(dx, dx), __fmul_rn(dy, dy)), __fmul_rn(dz, dz));
                mind[j] = fminf(mind[j], d);
                k[j] = ((unsigned long long)__float_as_uint(mind[j]) << 32)
                     | (unsigned)~(unsigned)(t + 256 * j);
            }
#pragma unroll
            for (int st = 8; st > 0; st >>= 1)
#pragma unroll
                for (int j = 0; j < st; ++j) k[j] = umax64(k[j], k[j + st]);
            unsigned long long key = k[0];
            {
                unsigned long long a = __shfl_xor(key, 1, 64);
                unsigned long long b2 = __shfl_xor(key, 2, 64);
                unsigned long long c = __shfl_xor(key, 3, 64);
                key = umax64(umax64(key, a), umax64(b2, c));
                a = __shfl_xor(key, 4, 64);
                b2 = __shfl_xor(key, 8, 64);
                c = __shfl_xor(key, 12, 64);
                key = umax64(umax64(key, a), umax64(b2, c));
                a = __shfl_xor(key, 16, 64);
                b2 = __shfl_xor(key, 32, 64);
                c = __shfl_xor(key, 48, 64);
                key = umax64(umax64(key, a), umax64(b2, c));
            }
            if (lane == 0) rk[p * 4 + wave] = key;
            __syncthreads();
            unsigned long long k0 = rk[p * 4 + 0], k1 = rk[p * 4 + 1];
            unsigned long long k2 = rk[p * 4 + 2], k3 = rk[p * 4 + 3];
            unsigned long long bk = umax64(umax64(k0, k1), umax64(k2, k3));
            int nx = (int)(~(unsigned)(bk & 0xFFFFFFFFull));
            cx = pxs[nx]; cy = pys[nx]; cz = pzs[nx];
            if (t == 0) {
                npb[s * 3 + 0] = cx;
                npb[s * 3 + 1] = cy;
                npb[s * 3 + 2] = cz;
            }
            if ((s & 7) == 7) {
                // flush last 8 samples (24 floats) to global, then release prog[b]=s
                if (t < 24) np[(s - 7) * 3 + t] = npb[(s - 7) * 3 + t];
                if (t == 0) {
                    __threadfence();
                    __hip_atomic_store(&prog[b], s, __ATOMIC_RELAXED, __HIP_MEMORY_SCOPE_AGENT);
                }
            }
        }
        return;
    }

    // ================= consumer: (b,s) = ballq + fused-xform + MFMA pointconv =================
    unsigned short* featl = (unsigned short*)smem;           // [128][104] bf16
    unsigned short* h2    = (unsigned short*)smem;           // [128][136] bf16 (aliases feat)
    unsigned short* h1    = (unsigned short*)(smem + 34816); // [128][72] bf16
    float* mred = (float*)(smem + 34816);                    // [4][512] fp32 (aliases h1)
    int*   vld  = (int*)(smem + 53248);                      // [128]
    int*   wl   = (int*)smem;                                // [4][128] (pre-featl)
    int*   cnt  = (int*)(smem + 2048);                       // [4]
    float* wtb  = (float*)(smem + 26624);                    // [256]: Wt 192 + bt 64

    int cons = blk - 8;
    int s = cons >> 3, b = cons & 7;
    int bs = b * 256 + s;
    int quad = lane >> 4, l16 = lane & 15;

    if (t == 0) {
        while (__hip_atomic_load(&prog[b], __ATOMIC_RELAXED, __HIP_MEMORY_SCOPE_AGENT) < s)
            __builtin_amdgcn_s_sleep(16);
    }
    __syncthreads();
    __threadfence();   // acquire: invalidate caches so newpos is fresh
    float q0 = newpos[(size_t)bs * 3 + 0];
    float q1 = newpos[(size_t)bs * 3 + 1];
    float q2 = newpos[(size_t)bs * 3 + 2];

    // ---- ball query: wave w scans [w*1024,(w+1)*1024), exact first-K-by-index
    const float* P = pos + (size_t)b * NPTS * 3;
    {
        int base = 0;
        for (int c = 0; c < 16 && base < KNBR; ++c) {
            int n = wave * 1024 + c * 64 + lane;
            float dx = __fsub_rn(P[n * 3 + 0], q0);
            float dy = __fsub_rn(P[n * 3 + 1], q1);
            float dz = __fsub_rn(P[n * 3 + 2], q2);
            float d2 = __fadd_rn(__fadd_rn(__fmul_rn(dx, dx), __fmul_rn(dy, dy)), __fmul_rn(dz, dz));
            bool in = (d2 <= 0.04f);
            unsigned long long mask = __ballot(in);
            if (in) {
                int p = base + __popcll(mask & ((1ull << lane) - 1ull));
                if (p < KNBR) wl[wave * 128 + p] = n;
            }
            base += __popcll(mask);
        }
        if (lane == 0) cnt[wave] = base < KNBR ? base : KNBR;
    }
    __syncthreads();
    {
        int c0 = cnt[0], c1 = cnt[1], c2 = cnt[2], c3 = cnt[3];
        if (t < 128) {
            int idx = -1, r = t;
            if (r < c0) idx = wl[r];
            else {
                r -= c0;
                if (r < c1) idx = wl[128 + r];
                else {
                    r -= c1;
                    if (r < c2) idx = wl[256 + r];
                    else { r -= c2; if (r < c3) idx = wl[384 + r]; }
                }
            }
            vld[t] = idx;
        }
        // stage Wt/bt into LDS (dead region between featl and h1)
        if (t < 192) wtb[t] = Wt[t];
        else wtb[t] = bt[t - 192];
    }
    __syncthreads();

    int vbits = 0;
#pragma unroll
    for (int i = 0; i < 2; ++i)
#pragma unroll
        for (int reg = 0; reg < 4; ++reg)
            if (vld[(2 * wave + i) * 16 + quad * 4 + reg] >= 0) vbits |= 1 << (i * 4 + reg);

    // ---- Phase A: fused xform -- compute feat row from pos directly (bit-identical to old xform)
    {
        int sr = t >> 1, sh = t & 1;
        int n = vld[sr];
        int ns = n < 0 ? 0 : n;
        const float* pp = pos + ((size_t)b * NPTS + ns) * 3;
        float p0 = pp[0], p1 = pp[1], p2 = pp[2];
        unsigned short* frow = &featl[sr * 104];
        u16x8 z8 = {0, 0, 0, 0, 0, 0, 0, 0};
        if (n >= 0) {
#pragma unroll
            for (int g = 0; g < 4; ++g) {
                u16x8 v8;
#pragma unroll
                for (int e = 0; e < 8; ++e) {
                    int c = sh * 32 + g * 8 + e;
                    float v = fmaf(p2, wtb[128 + c], fmaf(p1, wtb[64 + c], fmaf(p0, wtb[c], wtb[192 + c])));
                    v8[e] = (unsigned short)f2bf(lrelu01(v));
                }
                *(u16x8*)&frow[sh * 32 + g * 8] = v8;
            }
        } else {
#pragma unroll
            for (int g = 0; g < 4; ++g) *(u16x8*)&frow[sh * 32 + g * 8] = z8;
        }
        if (sh == 1) {
            u16x8 dv = z8;
            if (n >= 0) {
                dv[0] = (unsigned short)f2bf(__fsub_rn(p0, q0));
                dv[1] = (unsigned short)f2bf(__fsub_rn(p1, q1));
                dv[2] = (unsigned short)f2bf(__fsub_rn(p2, q2));
            }
            *(u16x8*)&frow[64] = dv;
            *(u16x8*)&frow[72] = z8;
            *(u16x8*)&frow[80] = z8;
            *(u16x8*)&frow[88] = z8;
        }
    }
    __syncthreads();

    // ---- Layer 1 MFMA: M=128, N=64, K=96
    {
        f32x4 acc[2][4];
#pragma unroll
        for (int i = 0; i < 2; ++i)
#pragma unroll
            for (int nt = 0; nt < 4; ++nt) acc[i][nt] = (f32x4){0.f, 0.f, 0.f, 0.f};
#pragma unroll
        for (int ks = 0; ks < 3; ++ks) {
            bf16x8 afr[2];
#pragma unroll
            for (int i = 0; i < 2; ++i)
                afr[i] = *(const bf16x8*)&featl[((2 * wave + i) * 16 + l16) * 104 + ks * 32 + quad * 8];
#pragma unroll
            for (int nt = 0; nt < 4; ++nt) {
                bf16x8 bfr = *(const bf16x8*)(W1T + (nt * 16 + l16) * 96 + ks * 32 + quad * 8);
                acc[0][nt] = MFMA16(afr[0], bfr, acc[0][nt]);
                acc[1][nt] = MFMA16(afr[1], bfr, acc[1][nt]);
            }
        }
#pragma unroll
        for (int i = 0; i < 2; ++i)
#pragma unroll
            for (int nt = 0; nt < 4; ++nt) {
                int col = nt * 16 + l16;
                float bias = bc1[col];
#pragma unroll
                for (int reg = 0; reg < 4; ++reg) {
                    int row = (2 * wave + i) * 16 + quad * 4 + reg;
                    h1[row * 72 + col] = f2bf(lrelu01(acc[i][nt][reg] + bias));
                }
            }
    }
    __syncthreads();

    // ---- Layer 2 MFMA: M=128, N=128, K=64 (h2 aliases feat)
    {
        f32x4 acc[2][8];
#pragma unroll
        for (int i = 0; i < 2; ++i)
#pragma unroll
            for (int nt = 0; nt < 8; ++nt) acc[i][nt] = (f32x4){0.f, 0.f, 0.f, 0.f};
#pragma unroll
        for (int ks = 0; ks < 2; ++ks) {
            bf16x8 afr[2];
#pragma unroll
            for (int i = 0; i < 2; ++i)
                afr[i] = *(const bf16x8*)&h1[((2 * wave + i) * 16 + l16) * 72 + ks * 32 + quad * 8];
#pragma unroll
            for (int nt = 0; nt < 8; ++nt) {
                bf16x8 bfr = *(const bf16x8*)(W2T + (nt * 16 + l16) * 64 + ks * 32 + quad * 8);
                acc[0][nt] = MFMA16(afr[0], bfr, acc[0][nt]);
                acc[1][nt] = MFMA16(afr[1], bfr, acc[1][nt]);
            }
        }
        __syncthreads();
#pragma unroll
        for (int i = 0; i < 2; ++i)
#pragma unroll
            for (int nt = 0; nt < 8; ++nt) {
                int col = nt * 16 + l16;
                float bias = bc2[col];
#pragma unroll
                for (int reg = 0; reg < 4; ++reg) {
                    int row = (2 * wave + i) * 16 + quad * 4 + reg;
                    h2[row * 136 + col] = f2bf(lrelu01(acc[i][nt][reg] + bias));
                }
            }
    }
    __syncthreads();

    // ---- Layer 3 MFMA: M=128, N=512, K=128; masked max
    for (int c3 = 0; c3 < 4; ++c3) {
        f32x4 acc[2][8];
#pragma unroll
        for (int i = 0; i < 2; ++i)
#pragma unroll
            for (int nt = 0; nt < 8; ++nt) acc[i][nt] = (f32x4){0.f, 0.f, 0.f, 0.f};
#pragma unroll
        for (int ks = 0; ks < 4; ++ks) {
            bf16x8 afr[2];
#pragma unroll
            for (int i = 0; i < 2; ++i)
                afr[i] = *(const bf16x8*)&h2[((2 * wave + i) * 16 + l16) * 136 + ks * 32 + quad * 8];
#pragma unroll
            for (int nt = 0; nt < 8; ++nt) {
                bf16x8 bfr = *(const bf16x8*)(W3T + ((size_t)((c3 * 8 + nt) * 16 + l16)) * 128 + ks * 32 + quad * 8);
                acc[0][nt] = MFMA16(afr[0], bfr, acc[0][nt]);
                acc[1][nt] = MFMA16(afr[1], bfr, acc[1][nt]);
            }
        }
#pragma unroll
        for (int nt = 0; nt < 8; ++nt) {
            float vmax = -3.402823466e+38f;
#pragma unroll
            for (int i = 0; i < 2; ++i)
#pragma unroll
                for (int reg = 0; reg < 4; ++reg)
                    if (vbits & (1 << (i * 4 + reg))) vmax = fmaxf(vmax, acc[i][nt][reg]);
            vmax = fmaxf(vmax, __shfl_xor(vmax, 16));
            vmax = fmaxf(vmax, __shfl_xor(vmax, 32));
            if (lane < 16) mred[wave * 512 + (c3 * 8 + nt) * 16 + l16] = vmax;
        }
    }
    __syncthreads();
    // ---- epilogue: encin row (bf16, K padded to 576): [agg | newpos | 0]
    unsigned short* erow = encin + (size_t)bs * 576;
    for (int c = t; c < 576; c += 256) {
        unsigned short v;
        if (c < 512) {
            float m4 = fmaxf(fmaxf(mred[c], mred[512 + c]), fmaxf(mred[1024 + c], mred[1536 + c]));
            v = f2bf(lrelu01(m4 + bc3[c]));
        } else if (c < 515) {
            v = f2bf(c == 512 ? q0 : (c == 513 ? q1 : q2));
        } else v = 0;
        erow[c] = v;
    }
}

// ---------------------------------------------------------------- generic bf16 MFMA GEMM: 128x128 tile
__global__ void __launch_bounds__(256, 3) mfma_gemm(
    const unsigned short* __restrict__ A, const unsigned short* __restrict__ BT,
    const float* __restrict__ bias, float* __restrict__ outf, unsigned short* __restrict__ outh,
    int M, int Ka, int Ncols, int act) {
    __shared__ __align__(16) unsigned short As[128 * 72];
    int t = threadIdx.x;
    int wave = t >> 6, lane = t & 63, quad = lane >> 4, l16 = lane & 15;
    int row0 = blockIdx.x * 128, col0 = blockIdx.y * 128;
    f32x4 acc[2][8];
#pragma unroll
    for (int i = 0; i < 2; ++i)
#pragma unroll
        for (int nt = 0; nt < 8; ++nt) acc[i][nt] = (f32x4){0.f, 0.f, 0.f, 0.f};
    int nk = Ka >> 6;
    int sr = t >> 1, sh = t & 1;
    int grow = row0 + sr; if (grow > M - 1) grow = M - 1;
    const unsigned short* Arow = A + (size_t)grow * Ka + sh * 32;
    for (int ks = 0; ks < nk; ++ks) {
        u16x8 av[4];
#pragma unroll
        for (int j = 0; j < 4; ++j) av[j] = *(const u16x8*)(Arow + ks * 64 + j * 8);
        __syncthreads();
#pragma unroll
        for (int j = 0; j < 4; ++j) *(u16x8*)&As[sr * 72 + sh * 32 + j * 8] = av[j];
        __syncthreads();
#pragma unroll
        for (int ks2 = 0; ks2 < 2; ++ks2) {
            bf16x8 afr[2];
            afr[0] = *(const bf16x8*)&As[((2 * wave) * 16 + l16) * 72 + ks2 * 32 + quad * 8];
            afr[1] = *(const bf16x8*)&As[((2 * wave + 1) * 16 + l16) * 72 + ks2 * 32 + quad * 8];
#pragma unroll
            for (int nt = 0; nt < 8; ++nt) {
                bf16x8 bfr = *(const bf16x8*)(BT + (size_t)(col0 + nt * 16 + l16) * Ka + ks * 64 + ks2 * 32 + quad * 8);
                acc[0][nt] = MFMA16(afr[0], bfr, acc[0][nt]);
                acc[1][nt] = MFMA16(afr[1], bfr, acc[1][nt]);
            }
        }
    }
#pragma unroll
    for (int i = 0; i < 2; ++i)
#pragma unroll
        for (int nt = 0; nt < 8; ++nt) {
            int col = col0 + nt * 16 + l16;
            float bv = bias[col];
#pragma unroll
            for (int reg = 0; reg < 4; ++reg) {
                int row = row0 + (2 * wave + i) * 16 + quad * 4 + reg;
                if (row < M) {
                    float v = acc[i][nt][reg] + bv;
                    if (act == 1) v = fmaxf(v, 0.f);
                    else if (act == 2) v = lrelu01(v);
                    if (outh) outh[(size_t)row * Ncols + col] = f2bf(v);
                    else outf[(size_t)row * Ncols + col] = v;
                }
            }
        }
}

// ---------------------------------------------------------------- vote aggregation (256 blocks)
__global__ void __launch_bounds__(256) votes_kernel(const float* __restrict__ e, float* __restrict__ z) {
    __shared__ float red[8][32][2];
    int blk = blockIdx.x;
    int b = blk >> 5, c0 = (blk & 31) << 5;
    int t = threadIdx.x, c = t & 31, sg = t >> 5;
    const float* eb = e + (size_t)b * SSAMP * 2048;
    float num = 0.f, den = 0.f;
    for (int si = 0; si < 32; ++si) {
        int s = sg * 32 + si;
        float mean = eb[(size_t)s * 2048 + c0 + c];
        float lv = eb[(size_t)s * 2048 + 1024 + c0 + c];
        float sd = expf(0.5f * lv);
        num += mean / sd;
        den += 1.f / sd;
    }
    red[sg][c][0] = num; red[sg][c][1] = den;
    __syncthreads();
    if (sg == 0) {
        float n = 0.f, d = 0.f;
#pragma unroll
        for (int k = 0; k < 8; ++k) { n += red[k][c][0]; d += red[k][c][1]; }
        z[b * 1024 + c0 + c] = n / d;
    }
}

// ---------------------------------------------------------------- u = z @ Wf[0:1024] + b (K-split x4)
__global__ void __launch_bounds__(256) ukern(const float* __restrict__ z,
                                             const float* __restrict__ Wf11, const float* __restrict__ bf11,
                                             const float* __restrict__ Wf21, const float* __restrict__ bf21,
                                             float* __restrict__ u1, float* __restrict__ u2) {
    __shared__ float zt[1024 * 8];      // zt[ci*8+r]
    __shared__ float red[4][64][8];
    const float* W = blockIdx.y ? Wf21 : Wf11;
    const float* bias = blockIdx.y ? bf21 : bf11;
    float* u = blockIdx.y ? u2 : u1;
    int t = threadIdx.x;
#pragma unroll
    for (int i = 0; i < 32; ++i) {
        int o = t + i * 256;
        zt[(o & 1023) * 8 + (o >> 10)] = z[o];
    }
    __syncthreads();
    int c64 = t & 63, kc = t >> 6;
    int co = blockIdx.x * 64 + c64;
    float acc[8];
#pragma unroll
    for (int r = 0; r < 8; ++r) acc[r] = 0.f;
    for (int i = 0; i < 256; ++i) {
        int ci = kc * 256 + i;
        float w = W[(size_t)ci * 512 + co];
        const float4* zp = (const float4*)&zt[ci * 8];
        float4 z0 = zp[0], z1 = zp[1];
        acc[0] = fmaf(z0.x, w, acc[0]); acc[1] = fmaf(z0.y, w, acc[1]);
        acc[2] = fmaf(z0.z, w, acc[2]); acc[3] = fmaf(z0.w, w, acc[3]);
        acc[4] = fmaf(z1.x, w, acc[4]); acc[5] = fmaf(z1.y, w, acc[5]);
        acc[6] = fmaf(z1.z, w, acc[6]); acc[7] = fmaf(z1.w, w, acc[7]);
    }
#pragma unroll
    for (int r = 0; r < 8; ++r) red[kc][c64][r] = acc[r];
    __syncthreads();
    if (kc == 0) {
#pragma unroll
        for (int r = 0; r < 8; ++r) {
            float v = red[0][c64][r] + red[1][c64][r] + red[2][c64][r] + red[3][c64][r] + bias[co];
            u[r * 512 + co] = v;
        }
    }
}

// ---------------------------------------------------------------- fold1 first layer -> bf16
__global__ void fold1_kernel(const float* __restrict__ u1, const float* __restrict__ Wf11,
                             unsigned short* __restrict__ f1) {
    int o = blockIdx.x * 256 + threadIdx.x;          // 8*2025*512 exact
    int co = o & 511;
    int rg = o >> 9;
    int b = rg / 2025;
    int g = rg - b * 2025;
    int i = g / 45, j = g - i * 45;
    float gx = (j == 44) ? 0.3f : (float)(-0.3 + j * (0.6 / 44.0));
    float gy = (i == 44) ? 0.3f : (float)(-0.3 + i * (0.6 / 44.0));
    float v = u1[(b << 9) + co];
    v = fmaf(gx, Wf11[1024 * 512 + co], v);
    v = fmaf(gy, Wf11[1025 * 512 + co], v);
    f1[o] = f2bf(fmaxf(v, 0.f));
}

// ---------------------------------------------------------------- fold2 first layer -> bf16
__global__ void fold2_kernel(const float* __restrict__ u2, const float* __restrict__ Wf21,
                             const float* __restrict__ pts, unsigned short* __restrict__ f2) {
    int o = blockIdx.x * 256 + threadIdx.x;
    int co = o & 511;
    int rg = o >> 9;
    int b = rg / 2025;
    float p0 = pts[rg * 3 + 0], p1 = pts[rg * 3 + 1], p2 = pts[rg * 3 + 2];
    float v = u2[(b << 9) + co];
    v = fmaf(p0, Wf21[1024 * 512 + co], v);
    v = fmaf(p1, Wf21[1025 * 512 + co], v);
    v = fmaf(p2, Wf21[1026 * 512 + co], v);
    f2[o] = f2bf(fmaxf(v, 0.f));
}

// ---------------------------------------------------------------- final 512->3 (one row per thread)
__global__ void smallout_kernel(const unsigned short* __restrict__ H, const float* __restrict__ Wf,
                                const float* __restrict__ bf, float* __restrict__ out, int rows) {
    int rg = blockIdx.x * 256 + threadIdx.x;
    if (rg >= rows) return;
    const unsigned int* h = (const unsigned int*)(H + (size_t)rg * 512);
    float a0 = bf[0], a1 = bf[1], a2 = bf[2];
#pragma unroll 4
    for (int q = 0; q < 256; ++q) {
        unsigned int p = h[q];
        float e0 = __uint_as_float(p << 16);
        float e1 = __uint_as_float(p & 0xFFFF0000u);
        int k = q * 2;
        a0 = fmaf(e0, Wf[k * 3 + 0], a0);
        a1 = fmaf(e0, Wf[k * 3 + 1], a1);
        a2 = fmaf(e0, Wf[k * 3 + 2], a2);
        a0 = fmaf(e1, Wf[k * 3 + 3], a0);
        a1 = fmaf(e1, Wf[k * 3 + 4], a1);
        a2 = fmaf(e1, Wf[k * 3 + 5], a2);
    }
    out[rg * 3 + 0] = a0;
    out[rg * 3 + 1] = a1;
    out[rg * 3 + 2] = a2;
}

extern "C" void kernel_launch(void* const* d_in, const int* in_sizes, int n_in,
                              void* d_out, int out_size, void* d_ws, size_t ws_size,
                              hipStream_t stream) {
    const float* pos  = (const float*)d_in[0];
    const float* Wt   = (const float*)d_in[1];
    const float* bt   = (const float*)d_in[2];
    const float* Wc1  = (const float*)d_in[3];
    const float* bc1  = (const float*)d_in[4];
    const float* Wc2  = (const float*)d_in[5];
    const float* bc2  = (const float*)d_in[6];
    const float* Wc3  = (const float*)d_in[7];
    const float* bc3  = (const float*)d_in[8];
    const float* We1  = (const float*)d_in[9];
    const float* be1  = (const float*)d_in[10];
    const float* We2  = (const float*)d_in[11];
    const float* be2  = (const float*)d_in[12];
    const float* Wf11 = (const float*)d_in[13];
    const float* bf11 = (const float*)d_in[14];
    const float* Wf12 = (const float*)d_in[15];
    const float* bf12 = (const float*)d_in[16];
    const float* Wf13 = (const float*)d_in[17];
    const float* bf13 = (const float*)d_in[18];
    const float* Wf21 = (const float*)d_in[19];
    const float* bf21 = (const float*)d_in[20];
    const float* Wf22 = (const float*)d_in[21];
    const float* bf22 = (const float*)d_in[22];
    const float* Wf23 = (const float*)d_in[23];
    const float* bf23 = (const float*)d_in[24];
    float* out = (float*)d_out;

    float* wsf = (float*)d_ws;
    size_t off = 0;
    unsigned short* encinh= (unsigned short*)(wsf + off); off += 589824;   // [2048][576] bf16
    unsigned short* e1h   = (unsigned short*)(wsf + off); off += 524288;   // [2048][512] bf16
    float* e    = wsf + off; off += 4194304;   // [2048][2048] fp32
    unsigned short* f1h   = (unsigned short*)(wsf + off); off += 4147200;  // [16200][512] bf16
    unsigned short* h12h  = (unsigned short*)(wsf + off); off += 4147200;  // [16200][512] bf16
    float* zb   = wsf + off; off += 8192;      // [8][1024]
    float* u1   = wsf + off; off += 4096;
    float* u2   = wsf + off; off += 4096;
    float* pts  = wsf + off; off += 48600;     // [16200][3]
    float* newp = wsf + off; off += 6144;      // [B,S,3]
    int*   prog = (int*)(wsf + off); off += 16;
    unsigned short* W1T   = (unsigned short*)(wsf + off); off += 3072;     // 64x96
    unsigned short* W2T   = (unsigned short*)(wsf + off); off += 4096;     // 128x64
    unsigned short* W3T   = (unsigned short*)(wsf + off); off += 32768;    // 512x128
    unsigned short* We1T  = (unsigned short*)(wsf + off); off += 147456;   // 512x576
    unsigned short* We2T  = (unsigned short*)(wsf + off); off += 524288;   // 2048x512
    unsigned short* Wf12T = (unsigned short*)(wsf + off); off += 131072;   // 512x512
    unsigned short* Wf22T = (unsigned short*)(wsf + off); off += 131072;   // 512x512

    hipMemsetAsync(prog, 0xFF, 64, stream);    // prog[b] = -1
    preconv_kernel<<<7608, 256, 0, stream>>>(Wc1, Wc2, Wc3, We1, We2, Wf12, Wf22,
                                             W1T, W2T, W3T, We1T, We2T, Wf12T, Wf22T);
    // stage1: 8 fps producers + 2048 (b,s) consumers (s-major order for dispatch liveness)
    stage1_kernel<<<2056, 256, 0, stream>>>(pos, newp, prog, Wt, bt, W1T, W2T, W3T,
                                            bc1, bc2, bc3, encinh);
    mfma_gemm<<<dim3(16, 4), 256, 0, stream>>>(encinh, We1T, be1, nullptr, e1h, 2048, 576, 512, 2);
    mfma_gemm<<<dim3(16, 16), 256, 0, stream>>>(e1h, We2T, be2, e, nullptr, 2048, 512, 2048, 0);
    votes_kernel<<<256, 256, 0, stream>>>(e, zb);
    ukern<<<dim3(8, 2), 256, 0, stream>>>(zb, Wf11, bf11, Wf21, bf21, u1, u2);
    fold1_kernel<<<32400, 256, 0, stream>>>(u1, Wf11, f1h);
    mfma_gemm<<<dim3(127, 4), 256, 0, stream>>>(f1h, Wf12T, bf12, nullptr, h12h, 16200, 512, 512, 1);
    smallout_kernel<<<64, 256, 0, stream>>>(h12h, Wf13, bf13, pts, 16200);
    fold2_kernel<<<32400, 256, 0, stream>>>(u2, Wf21, pts, f1h);
    mfma_gemm<<<dim3(127, 4), 256, 0, stream>>>(f1h, Wf22T, bf22, nullptr, h12h, 16200, 512, 512, 1);
    smallout_kernel<<<64, 256, 0, stream>>>(h12h, Wf23, bf23, out, 16200);
}